// Round 2
// baseline (1470.925 us; speedup 1.0000x reference)
//
#include <hip/hip_runtime.h>
#include <stdint.h>

#define FH 64
#define FW 64
#define CIN 1536
#define C3C 512
#define C4C 1024
#define COUT 512
#define BATCH 16
#define NPIX 4096
#define NBOX 10

typedef short v8s __attribute__((ext_vector_type(8)));
typedef float v4f __attribute__((ext_vector_type(4)));

__device__ __forceinline__ unsigned short f32_to_bf16(float f) {
    union { float f; uint32_t u; } v; v.f = f;
    uint32_t u = v.u;
    uint32_t r = (u + 0x7FFFu + ((u >> 16) & 1u)) >> 16;
    return (unsigned short)r;
}
__device__ __forceinline__ float bf16_to_f32(unsigned short h) {
    union { uint32_t u; float f; } v; v.u = ((uint32_t)h) << 16;
    return v.f;
}

// ---------------- BN constant folding -------------------------------------
__global__ void prep_bn(const float* __restrict__ bng, const float* __restrict__ bnb,
                        const float* __restrict__ bnm, const float* __restrict__ bnv,
                        const float* __restrict__ bconv,
                        float* __restrict__ scale, float* __restrict__ shift) {
    int o = threadIdx.x;
    if (o < COUT) {
        float inv = bng[o] / sqrtf(bnv[o] + 1e-5f);
        scale[o] = inv;
        shift[o] = bnb[o] + inv * (bconv[o] - bnm[o]);
    }
}

// ---------------- W f32 -> bf16 -------------------------------------------
__global__ void conv_w(const float* __restrict__ w, unsigned short* __restrict__ wbf, int n) {
    int i = blockIdx.x * 256 + threadIdx.x;
    if (i < n) wbf[i] = f32_to_bf16(w[i]);
}

// ---------------- build fusedT[b][pix][c] bf16 (K-major) -------------------
__global__ __launch_bounds__(256) void build_fusedT(const float* __restrict__ c3,
                                                    const float* __restrict__ c4,
                                                    unsigned short* __restrict__ fusedT) {
    __shared__ float lds[64][65];
    int ct = blockIdx.x;          // 0..23 (channel tile of 64)
    int y  = blockIdx.y;          // 0..63 (feature row)
    int b  = blockIdx.z;
    int t  = threadIdx.x;
    int c0 = ct * 64;
    int x  = t & 63;
    int r0 = t >> 6;              // 0..3

    if (c0 < C3C) {
        const float* src = c3 + (((size_t)(b * C3C + c0) * FH + y) * FW) + x;
        #pragma unroll
        for (int p = 0; p < 16; ++p) {
            int cr = r0 + p * 4;
            lds[cr][x] = src[(size_t)cr * (FH * FW)];
        }
    } else {
        int cc0 = c0 - C3C;
        int jy = y >> 1, fy = y & 1;
        int jyB = jy + (fy ? 1 : -1);
        jyB = min(max(jyB, 0), 31);
        int jx = x >> 1, fx = x & 1;
        int jxB = jx + (fx ? 1 : -1);
        jxB = min(max(jxB, 0), 31);
        const float* base = c4 + (size_t)(b * C4C + cc0) * (32 * 32);
        #pragma unroll
        for (int p = 0; p < 16; ++p) {
            int cr = r0 + p * 4;
            const float* pc = base + (size_t)cr * (32 * 32);
            float vA = pc[jy  * 32 + jx], vB = pc[jy  * 32 + jxB];
            float vC = pc[jyB * 32 + jx], vD = pc[jyB * 32 + jxB];
            lds[cr][x] = 0.75f * (0.75f * vA + 0.25f * vB)
                       + 0.25f * (0.75f * vC + 0.25f * vD);
        }
    }
    __syncthreads();
    int cl  = t & 63;
    int xr0 = t >> 6;
    unsigned short* dst = fusedT + ((size_t)b * NPIX + (size_t)y * FW) * CIN + c0 + cl;
    #pragma unroll
    for (int p = 0; p < 16; ++p) {
        int xr = xr0 + p * 4;
        dst[(size_t)xr * CIN] = f32_to_bf16(lds[cl][xr]);
    }
}

// ---------------- GEMM + BN + ReLU, channel-minor output -------------------
// attrT[b][pix][o] = relu(scale[o] * (fusedT[pix,:].W[o,:]) + shift[o])
// M = pixels (first operand), N = out-channels (second operand).
__global__ __launch_bounds__(256) void gemm_bn_relu(
        const unsigned short* __restrict__ wbf,
        const unsigned short* __restrict__ fusedT,
        const float* __restrict__ scale, const float* __restrict__ shift,
        unsigned short* __restrict__ attrT) {
    __shared__ __align__(16) unsigned short lds_a[128 * 32];  // W tile [o][k]
    __shared__ __align__(16) unsigned short lds_b[128 * 32];  // pix tile [pix][k]
    int t  = threadIdx.x;
    int n0 = blockIdx.x * 128;   // pixel tile
    int o0 = blockIdx.y * 128;   // out-channel tile
    int b  = blockIdx.z;
    int wave = t >> 6, lane = t & 63;
    int wm = wave & 1, wn = wave >> 1;   // wm: pixel half, wn: channel half
    int quad = lane >> 4, l16 = lane & 15;
    const unsigned short* fb = fusedT + (size_t)b * NPIX * CIN;

    v4f acc[4][4];
    #pragma unroll
    for (int i = 0; i < 4; ++i)
        #pragma unroll
        for (int j = 0; j < 4; ++j) acc[i][j] = (v4f)0.0f;

    int srow = t >> 1, shalf = t & 1;
    const uint4* asrc = (const uint4*)(wbf + (size_t)(o0 + srow) * CIN + shalf * 16);
    const uint4* bsrc = (const uint4*)(fb  + (size_t)(n0 + srow) * CIN + shalf * 16);
    uint4* adst = (uint4*)(lds_a + srow * 32 + shalf * 16);
    uint4* bdst = (uint4*)(lds_b + srow * 32 + shalf * 16);

    for (int kt = 0; kt < CIN / 32; ++kt) {
        uint4 a0 = asrc[0], a1 = asrc[1];
        uint4 b0 = bsrc[0], b1 = bsrc[1];
        asrc += 4; bsrc += 4;
        __syncthreads();
        adst[0] = a0; adst[1] = a1;
        bdst[0] = b0; bdst[1] = b1;
        __syncthreads();

        v8s pf[4], wf[4];
        #pragma unroll
        for (int i = 0; i < 4; ++i)      // pixel fragments (M operand)
            pf[i] = *(const v8s*)(lds_b + (wm * 64 + i * 16 + l16) * 32 + quad * 8);
        #pragma unroll
        for (int j = 0; j < 4; ++j)      // weight fragments (N operand)
            wf[j] = *(const v8s*)(lds_a + (wn * 64 + j * 16 + l16) * 32 + quad * 8);
        #pragma unroll
        for (int i = 0; i < 4; ++i)
            #pragma unroll
            for (int j = 0; j < 4; ++j)
                acc[i][j] = __builtin_amdgcn_mfma_f32_16x16x32_bf16(pf[i], wf[j], acc[i][j], 0, 0, 0);
    }

    unsigned short* ab = attrT + (size_t)b * NPIX * COUT;
    #pragma unroll
    for (int j = 0; j < 4; ++j) {
        int oo = o0 + wn * 64 + j * 16 + l16;       // col = lane&15 -> channel
        float sc = scale[oo], sh = shift[oo];
        #pragma unroll
        for (int i = 0; i < 4; ++i) {
            int pbase = n0 + wm * 64 + i * 16 + quad * 4;  // row = quad*4+r -> pixel
            #pragma unroll
            for (int r = 0; r < 4; ++r) {
                int pix = pbase + r;
                float v = acc[i][j][r] * sc + sh;
                v = fmaxf(v, 0.0f);
                ab[(size_t)pix * COUT + oo] = f32_to_bf16(v);
            }
        }
    }
}

// ---------------- adaptive ROI pool 5x5, channel-minor input ---------------
// one block per box; thread t owns channels 2t, 2t+1 (uint loads, coalesced)
__global__ __launch_bounds__(256) void roi_pool(const unsigned short* __restrict__ attrT,
                                                const float* __restrict__ boxes,
                                                float* __restrict__ out) {
    int br = blockIdx.x;                       // b*10 + r
    int b  = br / NBOX;
    int t  = threadIdx.x;
    const float* bx = boxes + (size_t)br * 4;
    int x1 = min(max((int)floorf(bx[0] * 0.125f), 0), 63);
    int y1 = min(max((int)floorf(bx[1] * 0.125f), 0), 63);
    int x2 = min(max((int)ceilf (bx[2] * 0.125f), 0), 63);
    int y2 = min(max((int)ceilf (bx[3] * 0.125f), 0), 63);
    if (x2 <= x1) x2 = min(x1 + 1, 64);
    if (y2 <= y1) y2 = min(y1 + 1, 64);
    int Lx = x2 - x1, Ly = y2 - y1;
    int sxk[5], exk[5], syk[5], eyk[5];
    float ivx[5], ivy[5];
    #pragma unroll
    for (int k = 0; k < 5; ++k) {
        sxk[k] = x1 + (k * Lx) / 5;
        exk[k] = x1 + ((k + 1) * Lx + 4) / 5;
        syk[k] = y1 + (k * Ly) / 5;
        eyk[k] = y1 + ((k + 1) * Ly + 4) / 5;
        ivx[k] = 1.0f / (float)(exk[k] - sxk[k]);
        ivy[k] = 1.0f / (float)(eyk[k] - syk[k]);
    }
    float a0[5][5] = {}, a1[5][5] = {};
    const uint32_t* base = (const uint32_t*)(attrT + (size_t)b * NPIX * COUT) + t;
    for (int h = y1; h < y2; ++h) {
        float s0[5] = {}, s1[5] = {};
        const uint32_t* row = base + (size_t)(h * FW) * (COUT / 2);
        for (int w = x1; w < x2; ++w) {
            uint32_t u = row[(size_t)w * (COUT / 2)];
            float v0 = bf16_to_f32((unsigned short)(u & 0xffffu));
            float v1 = bf16_to_f32((unsigned short)(u >> 16));
            #pragma unroll
            for (int q = 0; q < 5; ++q)
                if (w >= sxk[q] && w < exk[q]) {
                    s0[q] += ivx[q] * v0;
                    s1[q] += ivx[q] * v1;
                }
        }
        #pragma unroll
        for (int p = 0; p < 5; ++p)
            if (h >= syk[p] && h < eyk[p]) {
                #pragma unroll
                for (int q = 0; q < 5; ++q) {
                    a0[p][q] += ivy[p] * s0[q];
                    a1[p][q] += ivy[p] * s1[q];
                }
            }
    }
    int c0 = t * 2;
    float* op0 = out + 640 + ((size_t)br * COUT + c0) * 25;
    float* op1 = op0 + 25;
    #pragma unroll
    for (int p = 0; p < 5; ++p)
        #pragma unroll
        for (int q = 0; q < 5; ++q) {
            op0[p * 5 + q] = a0[p][q];
            op1[p * 5 + q] = a1[p][q];
        }
}

extern "C" void kernel_launch(void* const* d_in, const int* in_sizes, int n_in,
                              void* d_out, int out_size, void* d_ws, size_t ws_size,
                              hipStream_t stream) {
    const float* c3     = (const float*)d_in[0];
    const float* c4     = (const float*)d_in[1];
    const float* boxes  = (const float*)d_in[2];
    const float* w_conv = (const float*)d_in[3];
    const float* b_conv = (const float*)d_in[4];
    const float* bng    = (const float*)d_in[5];
    const float* bnb    = (const float*)d_in[6];
    const float* bnm    = (const float*)d_in[7];
    const float* bnv    = (const float*)d_in[8];
    float* out = (float*)d_out;

    char* ws = (char*)d_ws;
    // layout: fusedT bf16 [16][4096][1536] | wbf bf16 [512*1536] | scale | shift | attrT bf16 [16][4096][512]
    unsigned short* fusedT = (unsigned short*)ws;                       // 201326592 B
    unsigned short* wbf    = (unsigned short*)(ws + 201326592);         //   1572864 B
    float* scale           = (float*)(ws + 202899456);                  //      2048 B
    float* shift           = (float*)(ws + 202901504);                  //      2048 B
    unsigned short* attrT  = (unsigned short*)(ws + 202903552);         //  67108864 B

    hipMemcpyAsync(d_out, d_in[2], 640 * sizeof(float), hipMemcpyDeviceToDevice, stream);
    prep_bn<<<1, 512, 0, stream>>>(bng, bnb, bnm, bnv, b_conv, scale, shift);
    conv_w<<<(COUT * CIN + 255) / 256, 256, 0, stream>>>(w_conv, wbf, COUT * CIN);
    build_fusedT<<<dim3(24, 64, 16), 256, 0, stream>>>(c3, c4, fusedT);
    gemm_bn_relu<<<dim3(32, 4, 16), 256, 0, stream>>>(wbf, fusedT, scale, shift, attrT);
    roi_pool<<<160, 256, 0, stream>>>(attrT, boxes, out);
    (void)in_sizes; (void)n_in; (void)out_size; (void)ws_size;
}

// Round 3
// 683.694 us; speedup vs baseline: 2.1514x; 2.1514x over previous
//
#include <hip/hip_runtime.h>
#include <stdint.h>

#define FH 64
#define FW 64
#define CIN 1536
#define C3C 512
#define C4C 1024
#define COUT 512
#define BATCH 16
#define NPIX 4096
#define NBOX 10
#define NSLICE 8

typedef short v8s __attribute__((ext_vector_type(8)));
typedef float v4f __attribute__((ext_vector_type(4)));

__device__ __forceinline__ unsigned short f32_to_bf16(float f) {
    union { float f; uint32_t u; } v; v.f = f;
    uint32_t u = v.u;
    uint32_t r = (u + 0x7FFFu + ((u >> 16) & 1u)) >> 16;
    return (unsigned short)r;
}
__device__ __forceinline__ float bf16_to_f32(unsigned short h) {
    union { uint32_t u; float f; } v; v.u = ((uint32_t)h) << 16;
    return v.f;
}

// ---------------- BN constant folding -------------------------------------
__global__ void prep_bn(const float* __restrict__ bng, const float* __restrict__ bnb,
                        const float* __restrict__ bnm, const float* __restrict__ bnv,
                        const float* __restrict__ bconv,
                        float* __restrict__ scale, float* __restrict__ shift) {
    int o = threadIdx.x;
    if (o < COUT) {
        float inv = bng[o] / sqrtf(bnv[o] + 1e-5f);
        scale[o] = inv;
        shift[o] = bnb[o] + inv * (bconv[o] - bnm[o]);
    }
}

// ---------------- W f32 -> bf16 -------------------------------------------
__global__ void conv_w(const float* __restrict__ w, unsigned short* __restrict__ wbf, int n) {
    int i = blockIdx.x * 256 + threadIdx.x;
    if (i < n) wbf[i] = f32_to_bf16(w[i]);
}

// ---------------- build fusedT[b][pix][c] bf16 (K-major) -------------------
__global__ __launch_bounds__(256) void build_fusedT(const float* __restrict__ c3,
                                                    const float* __restrict__ c4,
                                                    unsigned short* __restrict__ fusedT) {
    __shared__ float lds[64][65];
    int ct = blockIdx.x;          // 0..23 (channel tile of 64)
    int y  = blockIdx.y;          // 0..63 (feature row)
    int b  = blockIdx.z;
    int t  = threadIdx.x;
    int c0 = ct * 64;
    int x  = t & 63;
    int r0 = t >> 6;              // 0..3

    if (c0 < C3C) {
        const float* src = c3 + (((size_t)(b * C3C + c0) * FH + y) * FW) + x;
        #pragma unroll
        for (int p = 0; p < 16; ++p) {
            int cr = r0 + p * 4;
            lds[cr][x] = src[(size_t)cr * (FH * FW)];
        }
    } else {
        int cc0 = c0 - C3C;
        int jy = y >> 1, fy = y & 1;
        int jyB = jy + (fy ? 1 : -1);
        jyB = min(max(jyB, 0), 31);
        int jx = x >> 1, fx = x & 1;
        int jxB = jx + (fx ? 1 : -1);
        jxB = min(max(jxB, 0), 31);
        const float* base = c4 + (size_t)(b * C4C + cc0) * (32 * 32);
        #pragma unroll
        for (int p = 0; p < 16; ++p) {
            int cr = r0 + p * 4;
            const float* pc = base + (size_t)cr * (32 * 32);
            float vA = pc[jy  * 32 + jx], vB = pc[jy  * 32 + jxB];
            float vC = pc[jyB * 32 + jx], vD = pc[jyB * 32 + jxB];
            lds[cr][x] = 0.75f * (0.75f * vA + 0.25f * vB)
                       + 0.25f * (0.75f * vC + 0.25f * vD);
        }
    }
    __syncthreads();
    int cl  = t & 63;
    int xr0 = t >> 6;
    unsigned short* dst = fusedT + ((size_t)b * NPIX + (size_t)y * FW) * CIN + c0 + cl;
    #pragma unroll
    for (int p = 0; p < 16; ++p) {
        int xr = xr0 + p * 4;
        dst[(size_t)xr * CIN] = f32_to_bf16(lds[cl][xr]);
    }
}

// ---------------- GEMM + BN + ReLU, channel-minor output -------------------
__global__ __launch_bounds__(256) void gemm_bn_relu(
        const unsigned short* __restrict__ wbf,
        const unsigned short* __restrict__ fusedT,
        const float* __restrict__ scale, const float* __restrict__ shift,
        unsigned short* __restrict__ attrT) {
    __shared__ __align__(16) unsigned short lds_a[128 * 32];  // W tile [o][k]
    __shared__ __align__(16) unsigned short lds_b[128 * 32];  // pix tile [pix][k]
    int t  = threadIdx.x;
    int n0 = blockIdx.x * 128;   // pixel tile
    int o0 = blockIdx.y * 128;   // out-channel tile
    int b  = blockIdx.z;
    int wave = t >> 6, lane = t & 63;
    int wm = wave & 1, wn = wave >> 1;
    int quad = lane >> 4, l16 = lane & 15;
    const unsigned short* fb = fusedT + (size_t)b * NPIX * CIN;

    v4f acc[4][4];
    #pragma unroll
    for (int i = 0; i < 4; ++i)
        #pragma unroll
        for (int j = 0; j < 4; ++j) acc[i][j] = (v4f)0.0f;

    int srow = t >> 1, shalf = t & 1;
    const uint4* asrc = (const uint4*)(wbf + (size_t)(o0 + srow) * CIN + shalf * 16);
    const uint4* bsrc = (const uint4*)(fb  + (size_t)(n0 + srow) * CIN + shalf * 16);
    uint4* adst = (uint4*)(lds_a + srow * 32 + shalf * 16);
    uint4* bdst = (uint4*)(lds_b + srow * 32 + shalf * 16);

    for (int kt = 0; kt < CIN / 32; ++kt) {
        uint4 a0 = asrc[0], a1 = asrc[1];
        uint4 b0 = bsrc[0], b1 = bsrc[1];
        asrc += 4; bsrc += 4;
        __syncthreads();
        adst[0] = a0; adst[1] = a1;
        bdst[0] = b0; bdst[1] = b1;
        __syncthreads();

        v8s pf[4], wf[4];
        #pragma unroll
        for (int i = 0; i < 4; ++i)
            pf[i] = *(const v8s*)(lds_b + (wm * 64 + i * 16 + l16) * 32 + quad * 8);
        #pragma unroll
        for (int j = 0; j < 4; ++j)
            wf[j] = *(const v8s*)(lds_a + (wn * 64 + j * 16 + l16) * 32 + quad * 8);
        #pragma unroll
        for (int i = 0; i < 4; ++i)
            #pragma unroll
            for (int j = 0; j < 4; ++j)
                acc[i][j] = __builtin_amdgcn_mfma_f32_16x16x32_bf16(pf[i], wf[j], acc[i][j], 0, 0, 0);
    }

    unsigned short* ab = attrT + (size_t)b * NPIX * COUT;
    #pragma unroll
    for (int j = 0; j < 4; ++j) {
        int oo = o0 + wn * 64 + j * 16 + l16;
        float sc = scale[oo], sh = shift[oo];
        #pragma unroll
        for (int i = 0; i < 4; ++i) {
            int pbase = n0 + wm * 64 + i * 16 + quad * 4;
            #pragma unroll
            for (int r = 0; r < 4; ++r) {
                int pix = pbase + r;
                float v = acc[i][j][r] * sc + sh;
                v = fmaxf(v, 0.0f);
                ab[(size_t)pix * COUT + oo] = f32_to_bf16(v);
            }
        }
    }
}

// ---------------- ROI pool phase 1: per-(box, row-slice) partials ----------
// grid (160, NSLICE); thread t owns channels 2t, 2t+1.
// part[slice][br][c][25] fully written (zeros if slice has no rows).
__global__ __launch_bounds__(256) void roi_pool_partial(
        const unsigned short* __restrict__ attrT,
        const float* __restrict__ boxes,
        float* __restrict__ part) {
    int br = blockIdx.x;
    int sl = blockIdx.y;
    int b  = br / NBOX;
    int t  = threadIdx.x;
    const float* bx = boxes + (size_t)br * 4;
    int x1 = min(max((int)floorf(bx[0] * 0.125f), 0), 63);
    int y1 = min(max((int)floorf(bx[1] * 0.125f), 0), 63);
    int x2 = min(max((int)ceilf (bx[2] * 0.125f), 0), 63);
    int y2 = min(max((int)ceilf (bx[3] * 0.125f), 0), 63);
    if (x2 <= x1) x2 = min(x1 + 1, 64);
    if (y2 <= y1) y2 = min(y1 + 1, 64);
    int Lx = x2 - x1, Ly = y2 - y1;
    int sxk[5], exk[5], syk[5], eyk[5];
    float ivx[5], ivy[5];
    #pragma unroll
    for (int k = 0; k < 5; ++k) {
        sxk[k] = x1 + (k * Lx) / 5;
        exk[k] = x1 + ((k + 1) * Lx + 4) / 5;
        syk[k] = y1 + (k * Ly) / 5;
        eyk[k] = y1 + ((k + 1) * Ly + 4) / 5;
        ivx[k] = 1.0f / (float)(exk[k] - sxk[k]);
        ivy[k] = 1.0f / (float)(eyk[k] - syk[k]);
    }
    float a0[5][5] = {}, a1[5][5] = {};
    const uint32_t* base = (const uint32_t*)(attrT + (size_t)b * NPIX * COUT) + t;
    for (int h = y1 + sl; h < y2; h += NSLICE) {
        float s0[5] = {}, s1[5] = {};
        const uint32_t* row = base + (size_t)(h * FW) * (COUT / 2);
        for (int w = x1; w < x2; ++w) {
            uint32_t u = row[(size_t)w * (COUT / 2)];
            float v0 = bf16_to_f32((unsigned short)(u & 0xffffu));
            float v1 = bf16_to_f32((unsigned short)(u >> 16));
            #pragma unroll
            for (int q = 0; q < 5; ++q)
                if (w >= sxk[q] && w < exk[q]) {
                    s0[q] += ivx[q] * v0;
                    s1[q] += ivx[q] * v1;
                }
        }
        #pragma unroll
        for (int p = 0; p < 5; ++p)
            if (h >= syk[p] && h < eyk[p]) {
                #pragma unroll
                for (int q = 0; q < 5; ++q) {
                    a0[p][q] += ivy[p] * s0[q];
                    a1[p][q] += ivy[p] * s1[q];
                }
            }
    }
    int c0 = t * 2;
    float* op = part + ((size_t)sl * 160 * COUT + (size_t)br * COUT + c0) * 25;
    #pragma unroll
    for (int p = 0; p < 5; ++p)
        #pragma unroll
        for (int q = 0; q < 5; ++q) {
            op[p * 5 + q]      = a0[p][q];
            op[25 + p * 5 + q] = a1[p][q];
        }
}

// ---------------- ROI pool phase 2: reduce NSLICE partials -----------------
__global__ __launch_bounds__(256) void roi_pool_reduce(const float* __restrict__ part,
                                                       float* __restrict__ out) {
    const int n = 160 * COUT * 25;
    int i = blockIdx.x * 256 + threadIdx.x;
    if (i >= n) return;
    float s = 0.0f;
    #pragma unroll
    for (int sl = 0; sl < NSLICE; ++sl) s += part[(size_t)sl * n + i];
    out[640 + i] = s;
}

extern "C" void kernel_launch(void* const* d_in, const int* in_sizes, int n_in,
                              void* d_out, int out_size, void* d_ws, size_t ws_size,
                              hipStream_t stream) {
    const float* c3     = (const float*)d_in[0];
    const float* c4     = (const float*)d_in[1];
    const float* boxes  = (const float*)d_in[2];
    const float* w_conv = (const float*)d_in[3];
    const float* b_conv = (const float*)d_in[4];
    const float* bng    = (const float*)d_in[5];
    const float* bnb    = (const float*)d_in[6];
    const float* bnm    = (const float*)d_in[7];
    const float* bnv    = (const float*)d_in[8];
    float* out = (float*)d_out;

    char* ws = (char*)d_ws;
    // layout: fusedT bf16 [16][4096][1536] | wbf | scale | shift | attrT bf16 [16][4096][512]
    // part f32 [8][160][512][25] ALIASES fusedT (dead after gemm; stream-ordered).
    unsigned short* fusedT = (unsigned short*)ws;                       // 201326592 B
    float* part            = (float*)ws;                                //  65536000 B (alias)
    unsigned short* wbf    = (unsigned short*)(ws + 201326592);         //   1572864 B
    float* scale           = (float*)(ws + 202899456);                  //      2048 B
    float* shift           = (float*)(ws + 202901504);                  //      2048 B
    unsigned short* attrT  = (unsigned short*)(ws + 202903552);         //  67108864 B

    hipMemcpyAsync(d_out, d_in[2], 640 * sizeof(float), hipMemcpyDeviceToDevice, stream);
    prep_bn<<<1, 512, 0, stream>>>(bng, bnb, bnm, bnv, b_conv, scale, shift);
    conv_w<<<(COUT * CIN + 255) / 256, 256, 0, stream>>>(w_conv, wbf, COUT * CIN);
    build_fusedT<<<dim3(24, 64, 16), 256, 0, stream>>>(c3, c4, fusedT);
    gemm_bn_relu<<<dim3(32, 4, 16), 256, 0, stream>>>(wbf, fusedT, scale, shift, attrT);
    roi_pool_partial<<<dim3(160, NSLICE), 256, 0, stream>>>(attrT, boxes, part);
    roi_pool_reduce<<<(160 * COUT * 25 + 255) / 256, 256, 0, stream>>>(part, out);
    (void)in_sizes; (void)n_in; (void)out_size; (void)ws_size;
}